// Round 5
// baseline (650.932 us; speedup 1.0000x reference)
//
#include <hip/hip_runtime.h>
#include <hip/hip_bf16.h>

typedef __attribute__((ext_vector_type(8))) short bf16x8;
typedef __attribute__((ext_vector_type(4))) float f32x4;

static __device__ __forceinline__ unsigned short f2bf(float f) {
    union { float f; unsigned u; } v; v.f = f;
    unsigned r = v.u + 0x7fffu + ((v.u >> 16) & 1u);
    return (unsigned short)(r >> 16);
}

#define GLOAD16(g, l) __builtin_amdgcn_global_load_lds( \
    (const __attribute__((address_space(1))) void*)(g), \
    (__attribute__((address_space(3))) void*)(l), 16, 0, 0)

// ---------------------------------------------------------------------------
// Weight conversion: fp32 -> bf16, plane-major for direct global->VGPR frag
// loads: dst[((k>>3)*N + n)*8 + (k&7)].
// WcT: N=256,K=512 (vv rows then vc rows); bW1T: N=512,K=512; uW1T: N=512,K=256
// ---------------------------------------------------------------------------
__global__ __launch_bounds__(256) void conv_weights(
    const float* __restrict__ Wvv, const float* __restrict__ Wvc,
    const float* __restrict__ bW1, const float* __restrict__ uW1,
    unsigned short* __restrict__ WcT, unsigned short* __restrict__ bW1T,
    unsigned short* __restrict__ uW1T)
{
    int idx = blockIdx.x * 256 + threadIdx.x;
    if (idx < 131072) {                       // WcT
        int n = idx & 255, k = idx >> 8;
        float s = (k < 256) ? Wvv[k * 256 + n] : Wvc[(k - 256) * 256 + n];
        WcT[((k >> 3) * 256 + n) * 8 + (k & 7)] = f2bf(s);
    } else if (idx < 131072 + 262144) {       // bW1T
        int t = idx - 131072;
        int n = t & 511, k = t >> 9;
        bW1T[((k >> 3) * 512 + n) * 8 + (k & 7)] = f2bf(bW1[k * 512 + n]);
    } else if (idx < 131072 + 262144 + 131072) { // uW1T
        int t = idx - 393216;
        int n = t & 511, k = t >> 9;
        uW1T[((k >> 3) * 512 + n) * 8 + (k & 7)] = f2bf(uW1[k * 512 + n]);
    }
}

// ---------------------------------------------------------------------------
// ha = relu(ha_prev @ W_vv + c_atom @ W_vc); ha[0]=0
// BM=128, N=256, K=512. 8 waves (2x4), 64x64 each. B direct from L2 (no LDS).
// A: fp32->bf16 reg-staged, LDS double-buffered, 1 barrier/step.
// ---------------------------------------------------------------------------
__global__ __launch_bounds__(512, 4) void ha_kernel(
    const float* __restrict__ ha_prev, const float* __restrict__ c_atom,
    const unsigned short* __restrict__ WcT, const int* __restrict__ mol_id,
    unsigned short* __restrict__ haB, float* __restrict__ hm, int NA)
{
    __shared__ __align__(16) unsigned short As[2][128 * 64];

    const int tid = threadIdx.x;
    const int wv = tid >> 6, lane = tid & 63;
    const int wr = wv >> 2, wc = wv & 3;
    const int c15 = lane & 15, kq = lane >> 4;
    const int xm3 = (c15 & 7) << 3;
    const int m0 = blockIdx.x * 128;

    const int cr0 = tid >> 3, chc = tid & 7;
    const int cr1 = (512 + tid) >> 3;
    int row0 = m0 + cr0; if (row0 >= NA) row0 = NA - 1;
    int row1 = m0 + cr1; if (row1 >= NA) row1 = NA - 1;

    f32x4 v00, v01, v10, v11;
    #define HA_LOAD(ks) { \
        const float* src = ((ks) < 4) ? ha_prev : c_atom; \
        const int kb = ((ks) & 3) * 64 + chc * 8; \
        const float* s0 = src + (size_t)row0 * 256 + kb; \
        const float* s1 = src + (size_t)row1 * 256 + kb; \
        v00 = *(const f32x4*)s0; v01 = *(const f32x4*)(s0 + 4); \
        v10 = *(const f32x4*)s1; v11 = *(const f32x4*)(s1 + 4); }
    #define HA_WRITE(buf) { \
        bf16x8 p0, p1; \
        p0[0]=(short)f2bf(v00[0]); p0[1]=(short)f2bf(v00[1]); p0[2]=(short)f2bf(v00[2]); p0[3]=(short)f2bf(v00[3]); \
        p0[4]=(short)f2bf(v01[0]); p0[5]=(short)f2bf(v01[1]); p0[6]=(short)f2bf(v01[2]); p0[7]=(short)f2bf(v01[3]); \
        p1[0]=(short)f2bf(v10[0]); p1[1]=(short)f2bf(v10[1]); p1[2]=(short)f2bf(v10[2]); p1[3]=(short)f2bf(v10[3]); \
        p1[4]=(short)f2bf(v11[0]); p1[5]=(short)f2bf(v11[1]); p1[6]=(short)f2bf(v11[2]); p1[7]=(short)f2bf(v11[3]); \
        *(bf16x8*)&As[buf][cr0 * 64 + ((chc * 8) ^ ((cr0 & 7) << 3))] = p0; \
        *(bf16x8*)&As[buf][cr1 * 64 + ((chc * 8) ^ ((cr1 & 7) << 3))] = p1; }

    f32x4 acc[4][4];
#pragma unroll
    for (int m = 0; m < 4; ++m)
#pragma unroll
        for (int n = 0; n < 4; ++n) acc[m][n] = (f32x4){0.f, 0.f, 0.f, 0.f};

    HA_LOAD(0); HA_WRITE(0);
    __syncthreads();

    for (int ks = 0; ks < 8; ++ks) {
        if (ks < 7) HA_LOAD(ks + 1);
        const int buf = ks & 1;
#pragma unroll
        for (int kk = 0; kk < 2; ++kk) {
            bf16x8 aF[4], bF[4];
            const int plane = ks * 8 + kk * 4 + kq;
#pragma unroll
            for (int n = 0; n < 4; ++n)
                bF[n] = *(const bf16x8*)(WcT + ((size_t)plane * 256 + wc * 64 + n * 16 + c15) * 8);
#pragma unroll
            for (int m = 0; m < 4; ++m)
                aF[m] = *(const bf16x8*)&As[buf][(wr * 64 + m * 16 + c15) * 64 + ((kk * 32 + kq * 8) ^ xm3)];
#pragma unroll
            for (int m = 0; m < 4; ++m)
#pragma unroll
                for (int n = 0; n < 4; ++n)
                    acc[m][n] = __builtin_amdgcn_mfma_f32_16x16x32_bf16(aF[m], bF[n], acc[m][n], 0, 0, 0);
        }
        if (ks < 7) HA_WRITE((ks + 1) & 1);
        __syncthreads();
    }

#pragma unroll
    for (int m = 0; m < 4; ++m) {
#pragma unroll
        for (int reg = 0; reg < 4; ++reg) {
            int row = m0 + wr * 64 + m * 16 + kq * 4 + reg;
            if (row >= NA) continue;
            bool z = (row == 0);
            int mol = z ? 0 : mol_id[row];
#pragma unroll
            for (int n = 0; n < 4; ++n) {
                int col = wc * 64 + n * 16 + c15;
                float v = fmaxf(acc[m][n][reg], 0.f);
                if (z) v = 0.f;
                haB[(size_t)row * 256 + col] = f2bf(v);
                if (!z) atomicAdd(&hm[mol * 256 + col], v);
            }
        }
    }
}

// ---------------------------------------------------------------------------
// bond: logits = relu([ha[b0]|ha[b1]] @ W1 + b1) @ W2 + b2, fully fused.
// BM=64 bonds, N=512, K=512. A resident in LDS as 8 planes [64 rows][128B]
// (the measured-conflict-free layout), staged via per-lane-source GLOAD16.
// B direct global->VGPR, 1-deep register prefetch, fully unrolled K loop.
// ---------------------------------------------------------------------------
__global__ __launch_bounds__(512, 4) void bond_kernel(
    const unsigned short* __restrict__ haB, const int* __restrict__ bidx,
    const unsigned short* __restrict__ bW1T, const float* __restrict__ b1,
    const float* __restrict__ W2, const float* __restrict__ b2,
    float* __restrict__ outB, int NB)
{
    __shared__ __align__(16) unsigned short As[8 * 64 * 64];  // 64 KB planes
    __shared__ float obuf[64][5];

    const int tid = threadIdx.x;
    const int wv = tid >> 6, lane = tid & 63;
    const int c15 = lane & 15, kq = lane >> 4;
    const int b0 = blockIdx.x * 64;

    if (tid < 320) ((float*)obuf)[tid] = 0.f;

    // stage A: wave wv stages plane kt=wv (endpoint wv>>2, k-offset (wv&3)*64).
    // GLOAD16 j writes rows j*8..j*8+7 of the plane; lane l -> row j*8+(l>>3),
    // chunk l&7 holds global chunk (l&7)^(row&7)  (XOR bank swizzle).
    {
        const int ep = wv >> 2, koff = (wv & 3) * 64;
        const int rsub = lane >> 3, csub = lane & 7;
        int eidxs[8];
#pragma unroll
        for (int j = 0; j < 8; ++j) {
            int gb = b0 + j * 8 + rsub; if (gb >= NB) gb = 0;
            eidxs[j] = bidx[gb * 2 + ep];
        }
#pragma unroll
        for (int j = 0; j < 8; ++j) {
            int r = j * 8 + rsub;
            GLOAD16(haB + (size_t)eidxs[j] * 256 + koff + (size_t)((csub ^ (r & 7)) * 8),
                    As + wv * 4096 + j * 512);
        }
    }
    __syncthreads();

    f32x4 acc[4][4];
#pragma unroll
    for (int m = 0; m < 4; ++m)
#pragma unroll
        for (int n = 0; n < 4; ++n) acc[m][n] = (f32x4){0.f, 0.f, 0.f, 0.f};

    // K loop: 16 steps (s = ks*2+kk), fully unrolled, bF prefetched 1 deep.
    bf16x8 breg[2][4];
    {
        const int pl0 = kq;
#pragma unroll
        for (int n = 0; n < 4; ++n)
            breg[0][n] = *(const bf16x8*)(bW1T + ((size_t)pl0 * 512 + wv * 64 + n * 16 + c15) * 8);
    }
#pragma unroll
    for (int s = 0; s < 16; ++s) {
        if (s < 15) {
            const int pl = ((s + 1) >> 1) * 8 + ((s + 1) & 1) * 4 + kq;
#pragma unroll
            for (int n = 0; n < 4; ++n)
                breg[(s + 1) & 1][n] = *(const bf16x8*)(bW1T + ((size_t)pl * 512 + wv * 64 + n * 16 + c15) * 8);
        }
        const int ks = s >> 1, kk = s & 1;
        bf16x8 aF[4];
#pragma unroll
        for (int m = 0; m < 4; ++m) {
            int r = m * 16 + c15;
            aF[m] = *(const bf16x8*)&As[ks * 4096 + r * 64 + (((kk * 4 + kq) ^ (r & 7)) * 8)];
        }
#pragma unroll
        for (int m = 0; m < 4; ++m)
#pragma unroll
            for (int n = 0; n < 4; ++n)
                acc[m][n] = __builtin_amdgcn_mfma_f32_16x16x32_bf16(aF[m], breg[s & 1][n], acc[m][n], 0, 0, 0);
    }

    // fused layer 2: this wave's 64 hidden cols -> 5 partials per row
    float b1c[4], w2c[4][5];
#pragma unroll
    for (int n = 0; n < 4; ++n) {
        int col = wv * 64 + n * 16 + c15;
        b1c[n] = b1[col];
#pragma unroll
        for (int j = 0; j < 5; ++j) w2c[n][j] = W2[col * 5 + j];
    }
#pragma unroll
    for (int m = 0; m < 4; ++m) {
#pragma unroll
        for (int reg = 0; reg < 4; ++reg) {
            float s[5] = {0.f, 0.f, 0.f, 0.f, 0.f};
#pragma unroll
            for (int n = 0; n < 4; ++n) {
                float p = fmaxf(acc[m][n][reg] + b1c[n], 0.f);
#pragma unroll
                for (int j = 0; j < 5; ++j) s[j] += p * w2c[n][j];
            }
#pragma unroll
            for (int off = 1; off < 16; off <<= 1)
#pragma unroll
                for (int j = 0; j < 5; ++j) s[j] += __shfl_xor(s[j], off);
            if (c15 == 0) {
                int rl = m * 16 + kq * 4 + reg;
#pragma unroll
                for (int j = 0; j < 5; ++j) atomicAdd(&obuf[rl][j], s[j]);
            }
        }
    }
    __syncthreads();
    {
        int r = tid >> 3, j = tid & 7;
        if (j < 5) {
            int row = b0 + r;
            if (row < NB) outB[(size_t)row * 5 + j] = obuf[r][j] + b2[j];
        }
    }
}

// ---------------------------------------------------------------------------
// uni: logits = relu(ha @ W1 + b1) @ W2 + b2. BM=64 atoms, N=512, K=256.
// A resident as 4 planes [64][128B]; B prefetched; fully unrolled (8 steps).
// ---------------------------------------------------------------------------
__global__ __launch_bounds__(512, 4) void uni_kernel(
    const unsigned short* __restrict__ haB, const unsigned short* __restrict__ uW1T,
    const float* __restrict__ b1, const float* __restrict__ W2,
    const float* __restrict__ b2, float* __restrict__ outU, int NA)
{
    __shared__ __align__(16) unsigned short As[4 * 64 * 64];  // 32 KB planes
    __shared__ float obuf[64];

    const int tid = threadIdx.x;
    const int wv = tid >> 6, lane = tid & 63;
    const int c15 = lane & 15, kq = lane >> 4;
    const int a0 = blockIdx.x * 64;

    if (tid < 64) obuf[tid] = 0.f;

    // stage A: wave wv stages plane kt=wv>>1, row-groups (wv&1)*4 + jj
    {
        const int kt = wv >> 1, koff = kt * 64;
        const int rsub = lane >> 3, csub = lane & 7;
#pragma unroll
        for (int jj = 0; jj < 4; ++jj) {
            int j = (wv & 1) * 4 + jj;
            int r = j * 8 + rsub;
            int ga = a0 + r; if (ga >= NA) ga = NA - 1;
            GLOAD16(haB + (size_t)ga * 256 + koff + (size_t)((csub ^ (r & 7)) * 8),
                    As + kt * 4096 + j * 512);
        }
    }
    __syncthreads();

    f32x4 acc[4][4];
#pragma unroll
    for (int m = 0; m < 4; ++m)
#pragma unroll
        for (int n = 0; n < 4; ++n) acc[m][n] = (f32x4){0.f, 0.f, 0.f, 0.f};

    bf16x8 breg[2][4];
    {
        const int pl0 = kq;
#pragma unroll
        for (int n = 0; n < 4; ++n)
            breg[0][n] = *(const bf16x8*)(uW1T + ((size_t)pl0 * 512 + wv * 64 + n * 16 + c15) * 8);
    }
#pragma unroll
    for (int s = 0; s < 8; ++s) {
        if (s < 7) {
            const int pl = ((s + 1) >> 1) * 8 + ((s + 1) & 1) * 4 + kq;
#pragma unroll
            for (int n = 0; n < 4; ++n)
                breg[(s + 1) & 1][n] = *(const bf16x8*)(uW1T + ((size_t)pl * 512 + wv * 64 + n * 16 + c15) * 8);
        }
        const int ks = s >> 1, kk = s & 1;
        bf16x8 aF[4];
#pragma unroll
        for (int m = 0; m < 4; ++m) {
            int r = m * 16 + c15;
            aF[m] = *(const bf16x8*)&As[ks * 4096 + r * 64 + (((kk * 4 + kq) ^ (r & 7)) * 8)];
        }
#pragma unroll
        for (int m = 0; m < 4; ++m)
#pragma unroll
            for (int n = 0; n < 4; ++n)
                acc[m][n] = __builtin_amdgcn_mfma_f32_16x16x32_bf16(aF[m], breg[s & 1][n], acc[m][n], 0, 0, 0);
    }

    float b1c[4], w2c[4];
#pragma unroll
    for (int n = 0; n < 4; ++n) {
        int col = wv * 64 + n * 16 + c15;
        b1c[n] = b1[col];
        w2c[n] = W2[col];
    }
#pragma unroll
    for (int m = 0; m < 4; ++m) {
#pragma unroll
        for (int reg = 0; reg < 4; ++reg) {
            float s = 0.f;
#pragma unroll
            for (int n = 0; n < 4; ++n)
                s += fmaxf(acc[m][n][reg] + b1c[n], 0.f) * w2c[n];
#pragma unroll
            for (int off = 1; off < 16; off <<= 1) s += __shfl_xor(s, off);
            if (c15 == 0) atomicAdd(&obuf[m * 16 + kq * 4 + reg], s);
        }
    }
    __syncthreads();
    if (tid < 64) {
        int row = a0 + tid;
        if (row < NA) outU[row] = obuf[tid] + b2[0];
    }
}

// ---------------------------------------------------------------------------
// done_logits: 4 molecules per block (W1 streamed once per 4 mols), fp32
// ---------------------------------------------------------------------------
__global__ __launch_bounds__(256) void done_kernel(
    const float* __restrict__ hm, const float* __restrict__ W1,
    const float* __restrict__ b1, const float* __restrict__ W2,
    const float* __restrict__ b2, float* __restrict__ outD, int NM)
{
    __shared__ float rsh[4][256];
    __shared__ float red[4][4];
    const int tid = threadIdx.x;
    const int wv = tid >> 6, lane = tid & 63;
    const int mol0 = blockIdx.x * 4;
#pragma unroll
    for (int q = 0; q < 4; ++q)
        rsh[q][tid] = (mol0 + q < NM) ? hm[(size_t)(mol0 + q) * 256 + tid] : 0.f;
    __syncthreads();
    float h[4][2];
#pragma unroll
    for (int q = 0; q < 4; ++q) { h[q][0] = 0.f; h[q][1] = 0.f; }
    for (int k = 0; k < 256; ++k) {
        float w0 = W1[k * 512 + tid];
        float w1 = W1[k * 512 + tid + 256];
#pragma unroll
        for (int q = 0; q < 4; ++q) {
            h[q][0] += rsh[q][k] * w0;
            h[q][1] += rsh[q][k] * w1;
        }
    }
    float bb0 = b1[tid], bb1v = b1[tid + 256];
    float ww0 = W2[tid], ww1 = W2[tid + 256];
#pragma unroll
    for (int q = 0; q < 4; ++q) {
        float p = fmaxf(h[q][0] + bb0, 0.f) * ww0 + fmaxf(h[q][1] + bb1v, 0.f) * ww1;
#pragma unroll
        for (int off = 1; off < 64; off <<= 1) p += __shfl_xor(p, off);
        if (lane == 0) red[q][wv] = p;
    }
    __syncthreads();
    if (tid < 4 && mol0 + tid < NM)
        outD[mol0 + tid] = red[tid][0] + red[tid][1] + red[tid][2] + red[tid][3] + b2[0];
}

// ---------------------------------------------------------------------------
extern "C" void kernel_launch(void* const* d_in, const int* in_sizes, int n_in,
                              void* d_out, int out_size, void* d_ws, size_t ws_size,
                              hipStream_t stream)
{
    const float* c_atom  = (const float*)d_in[0];
    const float* ha_prev = (const float*)d_in[1];
    const float* W_vv    = (const float*)d_in[2];
    const float* W_vc    = (const float*)d_in[3];
    const float* bW1     = (const float*)d_in[4];
    const float* bb1     = (const float*)d_in[5];
    const float* bW2     = (const float*)d_in[6];
    const float* bb2     = (const float*)d_in[7];
    const float* uW1     = (const float*)d_in[8];
    const float* ub1     = (const float*)d_in[9];
    const float* uW2     = (const float*)d_in[10];
    const float* ub2     = (const float*)d_in[11];
    const float* dW1     = (const float*)d_in[12];
    const float* db1     = (const float*)d_in[13];
    const float* dW2     = (const float*)d_in[14];
    const float* db2     = (const float*)d_in[15];
    const int* mol_id    = (const int*)d_in[16];
    const int* bidx      = (const int*)d_in[17];

    const int H = 256, BS = 5;
    const int NA = in_sizes[0] / H;
    const int NB = in_sizes[17] / 2;
    const int NM = out_size - NB * BS - NA;

    float* out  = (float*)d_out;
    float* outB = out;
    float* outU = out + (size_t)NB * BS;
    float* outD = outU + NA;

    char* ws = (char*)d_ws;
    size_t off = 0;
    unsigned short* haB = (unsigned short*)(ws + off);
    off += (size_t)NA * H * 2;            off = (off + 255) & ~(size_t)255;
    float* hm = (float*)(ws + off);
    off += (size_t)NM * H * 4;            off = (off + 255) & ~(size_t)255;
    unsigned short* WcT = (unsigned short*)(ws + off);
    off += (size_t)131072 * 2;            off = (off + 255) & ~(size_t)255;
    unsigned short* bW1T = (unsigned short*)(ws + off);
    off += (size_t)262144 * 2;            off = (off + 255) & ~(size_t)255;
    unsigned short* uW1T = (unsigned short*)(ws + off);

    hipMemsetAsync(hm, 0, (size_t)NM * H * 4, stream);
    conv_weights<<<2048, 256, 0, stream>>>(W_vv, W_vc, bW1, uW1, WcT, bW1T, uW1T);
    ha_kernel<<<(NA + 127) / 128, 512, 0, stream>>>(ha_prev, c_atom, WcT, mol_id, haB, hm, NA);
    bond_kernel<<<(NB + 63) / 64, 512, 0, stream>>>(haB, bidx, bW1T, bb1, bW2, bb2, outB, NB);
    uni_kernel<<<(NA + 63) / 64, 512, 0, stream>>>(haB, uW1T, ub1, uW2, ub2, outU, NA);
    done_kernel<<<(NM + 3) / 4, 256, 0, stream>>>(hm, dW1, db1, dW2, db2, outD, NM);
}